// Round 8
// baseline (356.153 us; speedup 1.0000x reference)
//
#include <hip/hip_runtime.h>

// PillarVFE fused.
// k1: 4 threads per voxel (8 pts each), register-only accumulation of masked
//     point moments P2(10)/T(4)/S(3); quad combine (xor1,2), per-lane
//     algebraic epilogue -> 65 f-moments, quad-level butterfly (xor4..32),
//     block reduce -> partials row. Last block (atomic counter) reduces all
//     rows -> per-channel a,b (fused finalize). Also writes per-voxel packed
//     record (-mean,-center bf16, cnt).
// k3: A=[xyzw,-mean,-ctr]*mask in MFMA K-slots, B=a*W'' bf16, C=0 -> D=a*x;
//     out = relu(b + max_rows D). One wave = one voxel/iter, prefetched.

typedef __attribute__((ext_vector_type(8))) short short8;     // 8 bf16
typedef __attribute__((ext_vector_type(16))) float floatx16;  // 32x32 MFMA C/D

namespace {
constexpr int V_    = 100000;
constexpr int P_    = 32;
constexpr int COUT  = 64;
constexpr int NF    = 10;
constexpr int NMOM  = 65;
constexpr int PSTRIDE = 72;
constexpr int K1_BLOCKS = 1563;   // 64 voxels/block (4 thr/voxel), ceil(100000/64)
constexpr int K3_BLOCKS = 3125;   // 12500 waves x 8 iters = 100000 exactly
constexpr int K3_WAVES  = 12500;
constexpr int K3_ITERS  = 8;

constexpr float VX_ = 0.16f, VY_ = 0.16f, VZ_ = 4.0f;
constexpr float XOFF_ = 0.08f, YOFF_ = -39.60f, ZOFF_ = -1.0f;
constexpr float EPS_ = 0.001f;
}

__device__ __forceinline__ unsigned f2bfu(float x) {  // RNE -> 16-bit value
  unsigned u = __builtin_bit_cast(unsigned, x);
  u += 0x7fffu + ((u >> 16) & 1u);
  return u >> 16;
}

// ---------------- Pass 1 (+fused finalize) ----------------
__global__ __launch_bounds__(256) void k1_stats(
    const float* __restrict__ vf, const int* __restrict__ npts,
    const int* __restrict__ coords, float* __restrict__ partials,
    int4* __restrict__ meanws, unsigned* __restrict__ counter,
    const float* __restrict__ Wm, const float* __restrict__ gamma,
    const float* __restrict__ beta, float* __restrict__ ab)
{
  __shared__ float red[4][NMOM];
  __shared__ float s1[8][NMOM];
  __shared__ double Sd[NMOM];
  __shared__ unsigned lastFlag;

  const int tid = threadIdx.x;
  const int gt  = blockIdx.x * 256 + tid;
  const int v   = gt >> 2;          // voxel
  const int sub = gt & 3;           // point-block within voxel (8 pts)
  const bool valid = v < V_;

  int cnt = 0;
  int4 cd = make_int4(0, 0, 0, 0);
  if (valid) {
    cnt = npts[v];
    cd  = ((const int4*)coords)[v];
  }

  // 8 independent float4 loads (this thread's 8 points)
  float4 q[8];
  const float4* base = (const float4*)vf + (size_t)v * P_ + sub * 8;
  #pragma unroll
  for (int i = 0; i < 8; ++i)
    q[i] = valid ? base[i] : make_float4(0.f, 0.f, 0.f, 0.f);

  float p2[10];
  #pragma unroll
  for (int i = 0; i < 10; ++i) p2[i] = 0.f;
  float tx = 0.f, ty = 0.f, tz = 0.f, tw = 0.f;
  float sx = 0.f, sy = 0.f, sz = 0.f;

  #pragma unroll
  for (int i = 0; i < 8; ++i) {
    const int p = sub * 8 + i;
    const float msk = (p < cnt) ? 1.f : 0.f;
    sx += q[i].x; sy += q[i].y; sz += q[i].z;
    const float ux = q[i].x * msk, uy = q[i].y * msk;
    const float uz = q[i].z * msk, uw = q[i].w * msk;
    tx += ux; ty += uy; tz += uz; tw += uw;
    p2[0] += ux*ux; p2[1] += ux*uy; p2[2] += ux*uz; p2[3] += ux*uw;
    p2[4] += uy*uy; p2[5] += uy*uz; p2[6] += uy*uw;
    p2[7] += uz*uz; p2[8] += uz*uw;
    p2[9] += uw*uw;
  }

  // combine the voxel's 4 threads (xor 1,2): 17 additive raw moments
  #pragma unroll
  for (int m = 1; m <= 2; m <<= 1) {
    sx += __shfl_xor(sx, m, 64); sy += __shfl_xor(sy, m, 64);
    sz += __shfl_xor(sz, m, 64);
    tx += __shfl_xor(tx, m, 64); ty += __shfl_xor(ty, m, 64);
    tz += __shfl_xor(tz, m, 64); tw += __shfl_xor(tw, m, 64);
    #pragma unroll
    for (int i = 0; i < 10; ++i) p2[i] += __shfl_xor(p2[i], m, 64);
  }

  float mom[NMOM];
  if (valid) {
    const float cf = (float)cnt;
    const float rinv = 1.f / cf;
    const float gx = sx * rinv, gy = sy * rinv, gz = sz * rinv;
    const float hx = (float)cd.w * VX_ + XOFF_;
    const float hy = (float)cd.z * VY_ + YOFF_;
    const float hz = (float)cd.y * VZ_ + ZOFF_;

    if (sub == 0) {   // packed record for k3
      unsigned nm01 = f2bfu(-gx) | (f2bfu(-gy) << 16);
      unsigned nm23 = f2bfu(-gz) | (f2bfu(-hx) << 16);
      unsigned nm45 = f2bfu(-hy) | (f2bfu(-hz) << 16);
      meanws[v] = make_int4((int)nm01, (int)nm23, (int)nm45, cnt);
    }

    // f-moment reconstruction (per-voxel, replicated across the quad):
    // M1_i = T[SIG[i]] - cnt*K[i]
    // M2_ij = P2[SIG i,SIG j] - K_i*T[SIG j] - K_j*T[SIG i] + cnt*K_i*K_j
    const int SIG[10] = {0,1,2,3, 0,1,2, 0,1,2};
    const float K[10] = {0.f,0.f,0.f,0.f, gx,gy,gz, hx,hy,hz};
    const float Tm[4] = {tx,ty,tz,tw};
    const int I44[4][4] = {{0,1,2,3},{1,4,5,6},{2,5,7,8},{3,6,8,9}};

    #pragma unroll
    for (int i = 0; i < 10; ++i) mom[i] = Tm[SIG[i]] - cf * K[i];
    int idx = NF;
    #pragma unroll
    for (int i = 0; i < 10; ++i)
      #pragma unroll
      for (int j = i; j < 10; ++j) {
        mom[idx++] = p2[I44[SIG[i]][SIG[j]]]
                   - K[i] * Tm[SIG[j]] - K[j] * Tm[SIG[i]]
                   + cf * K[i] * K[j];
      }
  } else {
    #pragma unroll
    for (int i = 0; i < NMOM; ++i) mom[i] = 0.f;
  }

  // quad-level butterfly: sums the wave's 16 quads (each voxel counted once)
  #pragma unroll
  for (int i = 0; i < NMOM; ++i) {
    float a = mom[i];
    #pragma unroll
    for (int m = 4; m <= 32; m <<= 1) a += __shfl_xor(a, m, 64);
    mom[i] = a;
  }
  if ((tid & 63) == 0) {
    int w = tid >> 6;
    #pragma unroll
    for (int i = 0; i < NMOM; ++i) red[w][i] = mom[i];
  }
  __syncthreads();
  if (tid < NMOM) {
    partials[blockIdx.x * PSTRIDE + tid] =
        (red[0][tid] + red[1][tid]) + (red[2][tid] + red[3][tid]);
  }
  __threadfence();   // make partials visible at device scope
  __syncthreads();
  if (tid == 0) {
    unsigned old = atomicAdd(counter, 1u);
    lastFlag = (old == (unsigned)(K1_BLOCKS - 1)) ? 1u : 0u;
  }
  __syncthreads();
  if (!lastFlag) return;
  __threadfence();   // acquire side

  // ---- fused finalize (last block only): reduce 1563 rows ----
  for (int s = tid; s < 8 * NMOM; s += 256) {   // 520 slots: 8 chunks x 65 cols
    const int col = s % NMOM;
    const int ch  = s / NMOM;
    const int rbeg = ch * 196;
    const int rend = (rbeg + 196 < K1_BLOCKS) ? rbeg + 196 : K1_BLOCKS;
    float a[8];
    #pragma unroll
    for (int j = 0; j < 8; ++j) a[j] = 0.f;
    for (int r = rbeg; r < rend; r += 8) {
      #pragma unroll
      for (int j = 0; j < 8; ++j) {
        const int rr = r + j;
        if (rr < rend) a[j] += partials[rr * PSTRIDE + col];
      }
    }
    s1[ch][col] = (((a[0]+a[1]) + (a[2]+a[3])) + ((a[4]+a[5]) + (a[6]+a[7])));
  }
  __syncthreads();
  if (tid < NMOM) {
    double d = 0.0;
    #pragma unroll
    for (int c = 0; c < 8; ++c) d += (double)s1[c][tid];
    Sd[tid] = d;
  }
  __syncthreads();
  if (tid < COUT) {
    const double N = (double)V_ * (double)P_;
    double w[NF];
    #pragma unroll
    for (int c = 0; c < NF; ++c) w[c] = (double)Wm[tid * NF + c];
    double mean = 0.0;
    #pragma unroll
    for (int c = 0; c < NF; ++c) mean += w[c] * Sd[c];
    mean /= N;
    double ex2 = 0.0;
    int idx = NF;
    #pragma unroll
    for (int c = 0; c < NF; ++c)
      #pragma unroll
      for (int c2 = c; c2 < NF; ++c2) {
        double coef = (c == c2) ? 1.0 : 2.0;
        ex2 += coef * w[c] * w[c2] * Sd[idx++];
      }
    ex2 /= N;
    double var = ex2 - mean * mean;
    double rs = 1.0 / sqrt(var + (double)EPS_);
    double a = (double)gamma[tid] * rs;
    double b = (double)beta[tid] - mean * a;
    ab[tid] = (float)a;
    ab[COUT + tid] = (float)b;
  }
}

// ---------------- Pass 3 ----------------
__global__ __launch_bounds__(256) void k3_mfma(
    const float* __restrict__ vf, const float* __restrict__ Wm,
    const float* __restrict__ ab, const int4* __restrict__ meanws,
    float* __restrict__ out)
{
  const int tid  = threadIdx.x;
  const int lane = tid & 63;
  const int p    = lane & 31;
  const int half = lane >> 5;
  const int waveG = blockIdx.x * 4 + (tid >> 6);   // 0..12499

  // B fragments: B[k][n], n = lane&31, k = half*8+j.
  // k0..3: a*(W0+W4+W7, W1+W5+W8, W2+W6+W9, W3); k4..9: a*(W4..W9).
  const float a0 = ab[p],      b0 = ab[COUT + p];
  const float a1 = ab[32 + p], b1 = ab[COUT + 32 + p];
  short8 bf0, bf1;
  {
    const float* w0 = &Wm[p * NF];
    const float* w1 = &Wm[(32 + p) * NF];
    float t0[NF], t1[NF];
    t0[0] = a0 * (w0[0] + w0[4] + w0[7]);
    t0[1] = a0 * (w0[1] + w0[5] + w0[8]);
    t0[2] = a0 * (w0[2] + w0[6] + w0[9]);
    t0[3] = a0 * w0[3];
    t1[0] = a1 * (w1[0] + w1[4] + w1[7]);
    t1[1] = a1 * (w1[1] + w1[5] + w1[8]);
    t1[2] = a1 * (w1[2] + w1[6] + w1[9]);
    t1[3] = a1 * w1[3];
    #pragma unroll
    for (int k = 4; k < NF; ++k) { t0[k] = a0 * w0[k]; t1[k] = a1 * w1[k]; }

    uint4 bd0, bd1;
    unsigned p001 = f2bfu(t0[0]) | (f2bfu(t0[1]) << 16);
    unsigned p023 = f2bfu(t0[2]) | (f2bfu(t0[3]) << 16);
    unsigned p045 = f2bfu(t0[4]) | (f2bfu(t0[5]) << 16);
    unsigned p067 = f2bfu(t0[6]) | (f2bfu(t0[7]) << 16);
    unsigned p089 = f2bfu(t0[8]) | (f2bfu(t0[9]) << 16);
    unsigned p101 = f2bfu(t1[0]) | (f2bfu(t1[1]) << 16);
    unsigned p123 = f2bfu(t1[2]) | (f2bfu(t1[3]) << 16);
    unsigned p145 = f2bfu(t1[4]) | (f2bfu(t1[5]) << 16);
    unsigned p167 = f2bfu(t1[6]) | (f2bfu(t1[7]) << 16);
    unsigned p189 = f2bfu(t1[8]) | (f2bfu(t1[9]) << 16);
    bd0.x = half ? p089 : p001;  bd0.y = half ? 0u : p023;
    bd0.z = half ? 0u : p045;    bd0.w = half ? 0u : p067;
    bd1.x = half ? p189 : p101;  bd1.y = half ? 0u : p123;
    bd1.z = half ? 0u : p145;    bd1.w = half ? 0u : p167;
    bf0 = __builtin_bit_cast(short8, bd0);
    bf1 = __builtin_bit_cast(short8, bd1);
  }

  // prefetch iteration 0
  int vu = __builtin_amdgcn_readfirstlane(waveG);
  int4   rec_n = meanws[vu];
  float4 pt_n  = ((const float4*)vf)[vu * P_ + p];

  #pragma unroll
  for (int it = 0; it < K3_ITERS; ++it) {
    const int4   rec = rec_n;
    const float4 pt  = pt_n;
    const int vcur = vu;
    if (it + 1 < K3_ITERS) {
      vu = __builtin_amdgcn_readfirstlane(waveG + (it + 1) * K3_WAVES);
      rec_n = meanws[vu];
      pt_n  = ((const float4*)vf)[vu * P_ + p];
    }

    const int cnt = rec.w;
    const bool pm = p < cnt;
    unsigned dx = f2bfu(pm ? pt.x : 0.f) | (f2bfu(pm ? pt.y : 0.f) << 16);
    unsigned dy = f2bfu(pm ? pt.z : 0.f) | (f2bfu(pm ? pt.w : 0.f) << 16);
    unsigned m01 = pm ? (unsigned)rec.x : 0u;
    unsigned m23 = pm ? (unsigned)rec.y : 0u;
    unsigned m45 = pm ? (unsigned)rec.z : 0u;
    uint4 adw;
    adw.x = half ? m45 : dx;
    adw.y = half ? 0u  : dy;
    adw.z = half ? 0u  : m01;
    adw.w = half ? 0u  : m23;
    short8 af = __builtin_bit_cast(short8, adw);

    floatx16 c0 = {}, c1 = {};
    c0 = __builtin_amdgcn_mfma_f32_32x32x16_bf16(af, bf0, c0, 0, 0, 0);
    c1 = __builtin_amdgcn_mfma_f32_32x32x16_bf16(af, bf1, c1, 0, 0, 0);

    float m0 = c0[0], m1 = c1[0];
    #pragma unroll
    for (int i = 1; i < 16; ++i) {
      m0 = fmaxf(m0, c0[i]);
      m1 = fmaxf(m1, c1[i]);
    }
    m0 = fmaxf(m0, __shfl_xor(m0, 32, 64));
    m1 = fmaxf(m1, __shfl_xor(m1, 32, 64));
    float y = half ? fmaxf(b1 + m1, 0.f) : fmaxf(b0 + m0, 0.f);
    out[vcur * COUT + lane] = y;
  }
}

extern "C" void kernel_launch(void* const* d_in, const int* in_sizes, int n_in,
                              void* d_out, int out_size, void* d_ws, size_t ws_size,
                              hipStream_t stream)
{
  const float* vf     = (const float*)d_in[0];
  const int*   npts   = (const int*)d_in[1];
  const int*   coords = (const int*)d_in[2];
  const float* Wm     = (const float*)d_in[3];
  const float* gamma  = (const float*)d_in[4];
  const float* beta   = (const float*)d_in[5];
  float* out = (float*)d_out;

  float* ws = (float*)d_ws;
  float*    partials = ws;                                   // 1563*72 = 112536 floats
  float*    ab       = ws + K1_BLOCKS * PSTRIDE;             // 128 floats
  unsigned* counter  = (unsigned*)(ws + K1_BLOCKS * PSTRIDE + 128);   // idx 112664
  int4*     meanws   = (int4*)(ws + K1_BLOCKS * PSTRIDE + 132);       // idx 112668 (16B-aligned)

  hipMemsetAsync(counter, 0, sizeof(unsigned), stream);
  k1_stats<<<K1_BLOCKS, 256, 0, stream>>>(vf, npts, coords, partials, meanws,
                                          counter, Wm, gamma, beta, ab);
  k3_mfma<<<K3_BLOCKS, 256, 0, stream>>>(vf, Wm, ab, meanws, out);
}

// Round 9
// 211.889 us; speedup vs baseline: 1.6808x; 1.6808x over previous
//
#include <hip/hip_runtime.h>

// PillarVFE fused, 3 kernels (NO device fences / cross-block handoff:
// measured R7/R8, device-scope __threadfence per block costs ~0.17us each).
// k1: 8 threads/voxel (4 pts each), fully-coalesced loads, register moments
//     P2(10)/T(4)/S(3), octet shuffle-combine, per-lane algebraic epilogue
//     -> 65 f-moments, butterfly {8,16,32} + block reduce -> partials row.
//     Writes per-voxel packed record (-mean,-center bf16, cnt).
// k2: one 1024-thread block reduces 3125 rows -> per-channel a,b.
// k3: A=[xyzw,-mean,-ctr]*mask in MFMA K-slots, B=a*W'' bf16, C=0 -> D=a*x;
//     out = relu(b + max_rows D). One wave = one voxel/iter, prefetched.

typedef __attribute__((ext_vector_type(8))) short short8;     // 8 bf16
typedef __attribute__((ext_vector_type(16))) float floatx16;  // 32x32 MFMA C/D

namespace {
constexpr int V_    = 100000;
constexpr int P_    = 32;
constexpr int COUT  = 64;
constexpr int NF    = 10;
constexpr int NMOM  = 65;
constexpr int PSTRIDE = 72;
constexpr int K1_BLOCKS = 3125;   // 32 voxels/block (8 thr/voxel) -> exact
constexpr int K2_CHUNKS = 15;     // 15 x 209 rows >= 3125
constexpr int K3_BLOCKS = 3125;   // 12500 waves x 8 iters = 100000 exactly
constexpr int K3_WAVES  = 12500;
constexpr int K3_ITERS  = 8;

constexpr float VX_ = 0.16f, VY_ = 0.16f, VZ_ = 4.0f;
constexpr float XOFF_ = 0.08f, YOFF_ = -39.60f, ZOFF_ = -1.0f;
constexpr float EPS_ = 0.001f;
}

__device__ __forceinline__ unsigned f2bfu(float x) {  // RNE -> 16-bit value
  unsigned u = __builtin_bit_cast(unsigned, x);
  u += 0x7fffu + ((u >> 16) & 1u);
  return u >> 16;
}

// ---------------- Pass 1 ----------------
__global__ __launch_bounds__(256) void k1_stats(
    const float* __restrict__ vf, const int* __restrict__ npts,
    const int* __restrict__ coords, float* __restrict__ partials,
    int4* __restrict__ meanws)
{
  __shared__ float red[4][NMOM];

  const int tid = threadIdx.x;
  const int gt  = blockIdx.x * 256 + tid;
  const int v   = gt >> 3;          // voxel (exact: 3125*32 = 100000)
  const int oct = gt & 7;           // 4-point slice within voxel

  const int  cnt = npts[v];
  const int4 cd  = ((const int4*)coords)[v];

  // 4 float4 loads: lane-contiguous 64B/thread -> wave covers 4KB contiguous
  float4 q[4];
  const float4* base = (const float4*)vf + (size_t)v * P_ + oct * 4;
  #pragma unroll
  for (int i = 0; i < 4; ++i) q[i] = base[i];

  float p2[10];
  #pragma unroll
  for (int i = 0; i < 10; ++i) p2[i] = 0.f;
  float tx = 0.f, ty = 0.f, tz = 0.f, tw = 0.f;
  float sx = 0.f, sy = 0.f, sz = 0.f;

  #pragma unroll
  for (int i = 0; i < 4; ++i) {
    const int p = oct * 4 + i;
    const float msk = (p < cnt) ? 1.f : 0.f;
    sx += q[i].x; sy += q[i].y; sz += q[i].z;
    const float ux = q[i].x * msk, uy = q[i].y * msk;
    const float uz = q[i].z * msk, uw = q[i].w * msk;
    tx += ux; ty += uy; tz += uz; tw += uw;
    p2[0] += ux*ux; p2[1] += ux*uy; p2[2] += ux*uz; p2[3] += ux*uw;
    p2[4] += uy*uy; p2[5] += uy*uz; p2[6] += uy*uw;
    p2[7] += uz*uz; p2[8] += uz*uw;
    p2[9] += uw*uw;
  }

  // combine the voxel's 8 threads (xor 1,2,4): 17 additive raw moments
  #pragma unroll
  for (int m = 1; m <= 4; m <<= 1) {
    sx += __shfl_xor(sx, m, 64); sy += __shfl_xor(sy, m, 64);
    sz += __shfl_xor(sz, m, 64);
    tx += __shfl_xor(tx, m, 64); ty += __shfl_xor(ty, m, 64);
    tz += __shfl_xor(tz, m, 64); tw += __shfl_xor(tw, m, 64);
    #pragma unroll
    for (int i = 0; i < 10; ++i) p2[i] += __shfl_xor(p2[i], m, 64);
  }

  const float cf = (cnt > 0) ? (float)cnt : 1.f;
  const float rinv = 1.f / cf;
  const float gx = sx * rinv, gy = sy * rinv, gz = sz * rinv;
  const float hx = (float)cd.w * VX_ + XOFF_;
  const float hy = (float)cd.z * VY_ + YOFF_;
  const float hz = (float)cd.y * VZ_ + ZOFF_;

  if (oct == 0) {   // packed record for k3
    unsigned nm01 = f2bfu(-gx) | (f2bfu(-gy) << 16);
    unsigned nm23 = f2bfu(-gz) | (f2bfu(-hx) << 16);
    unsigned nm45 = f2bfu(-hy) | (f2bfu(-hz) << 16);
    meanws[v] = make_int4((int)nm01, (int)nm23, (int)nm45, cnt);
  }

  // f-moment reconstruction (replicated across octet):
  // M1_i = T[SIG[i]] - cnt*K[i]
  // M2_ij = P2[SIG i,SIG j] - K_i*T[SIG j] - K_j*T[SIG i] + cnt*K_i*K_j
  float mom[NMOM];
  {
    const int SIG[10] = {0,1,2,3, 0,1,2, 0,1,2};
    const float K[10] = {0.f,0.f,0.f,0.f, gx,gy,gz, hx,hy,hz};
    const float Tm[4] = {tx,ty,tz,tw};
    const int I44[4][4] = {{0,1,2,3},{1,4,5,6},{2,5,7,8},{3,6,8,9}};

    #pragma unroll
    for (int i = 0; i < 10; ++i) mom[i] = Tm[SIG[i]] - cf * K[i];
    int idx = NF;
    #pragma unroll
    for (int i = 0; i < 10; ++i)
      #pragma unroll
      for (int j = i; j < 10; ++j) {
        mom[idx++] = p2[I44[SIG[i]][SIG[j]]]
                   - K[i] * Tm[SIG[j]] - K[j] * Tm[SIG[i]]
                   + cf * K[i] * K[j];
      }
  }

  // octet-level butterfly: sums the wave's 8 octets (each voxel once)
  #pragma unroll
  for (int i = 0; i < NMOM; ++i) {
    float a = mom[i];
    #pragma unroll
    for (int m = 8; m <= 32; m <<= 1) a += __shfl_xor(a, m, 64);
    mom[i] = a;
  }
  if ((tid & 63) == 0) {
    int w = tid >> 6;
    #pragma unroll
    for (int i = 0; i < NMOM; ++i) red[w][i] = mom[i];
  }
  __syncthreads();
  if (tid < NMOM) {
    partials[blockIdx.x * PSTRIDE + tid] =
        (red[0][tid] + red[1][tid]) + (red[2][tid] + red[3][tid]);
  }
}

// ---------------- Pass 2: reduce 3125 rows -> a,b ----------------
__global__ __launch_bounds__(1024) void k2_finalize(
    const float* __restrict__ partials, const float* __restrict__ Wm,
    const float* __restrict__ gamma, const float* __restrict__ beta,
    float* __restrict__ ab)
{
  __shared__ float s1[K2_CHUNKS][NMOM];
  __shared__ double Sd[NMOM];
  const int t = threadIdx.x;

  if (t < K2_CHUNKS * NMOM) {   // 975 threads: 15 chunks x 209 rows
    const int col = t % NMOM, ch = t / NMOM;
    const int rbeg = ch * 209;
    const int rend = (rbeg + 209 < K1_BLOCKS) ? rbeg + 209 : K1_BLOCKS;
    float a[8];
    #pragma unroll
    for (int j = 0; j < 8; ++j) a[j] = 0.f;
    for (int r = rbeg; r < rend; r += 8) {
      #pragma unroll
      for (int j = 0; j < 8; ++j) {
        const int rr = r + j;
        if (rr < rend) a[j] += partials[rr * PSTRIDE + col];
      }
    }
    s1[ch][col] = (((a[0]+a[1]) + (a[2]+a[3])) + ((a[4]+a[5]) + (a[6]+a[7])));
  }
  __syncthreads();
  if (t < NMOM) {
    double d = 0.0;
    #pragma unroll
    for (int c = 0; c < K2_CHUNKS; ++c) d += (double)s1[c][t];
    Sd[t] = d;
  }
  __syncthreads();
  if (t < COUT) {
    const double N = (double)V_ * (double)P_;
    double w[NF];
    #pragma unroll
    for (int c = 0; c < NF; ++c) w[c] = (double)Wm[t * NF + c];
    double mean = 0.0;
    #pragma unroll
    for (int c = 0; c < NF; ++c) mean += w[c] * Sd[c];
    mean /= N;
    double ex2 = 0.0;
    int idx = NF;
    #pragma unroll
    for (int c = 0; c < NF; ++c)
      #pragma unroll
      for (int c2 = c; c2 < NF; ++c2) {
        double coef = (c == c2) ? 1.0 : 2.0;
        ex2 += coef * w[c] * w[c2] * Sd[idx++];
      }
    ex2 /= N;
    double var = ex2 - mean * mean;
    double rs = 1.0 / sqrt(var + (double)EPS_);
    double a = (double)gamma[t] * rs;
    double b = (double)beta[t] - mean * a;
    ab[t] = (float)a;
    ab[COUT + t] = (float)b;
  }
}

// ---------------- Pass 3 ----------------
__global__ __launch_bounds__(256) void k3_mfma(
    const float* __restrict__ vf, const float* __restrict__ Wm,
    const float* __restrict__ ab, const int4* __restrict__ meanws,
    float* __restrict__ out)
{
  const int tid  = threadIdx.x;
  const int lane = tid & 63;
  const int p    = lane & 31;
  const int half = lane >> 5;
  const int waveG = blockIdx.x * 4 + (tid >> 6);   // 0..12499

  // B fragments: B[k][n], n = lane&31, k = half*8+j.
  // k0..3: a*(W0+W4+W7, W1+W5+W8, W2+W6+W9, W3); k4..9: a*(W4..W9).
  const float a0 = ab[p],      b0 = ab[COUT + p];
  const float a1 = ab[32 + p], b1 = ab[COUT + 32 + p];
  short8 bf0, bf1;
  {
    const float* w0 = &Wm[p * NF];
    const float* w1 = &Wm[(32 + p) * NF];
    float t0[NF], t1[NF];
    t0[0] = a0 * (w0[0] + w0[4] + w0[7]);
    t0[1] = a0 * (w0[1] + w0[5] + w0[8]);
    t0[2] = a0 * (w0[2] + w0[6] + w0[9]);
    t0[3] = a0 * w0[3];
    t1[0] = a1 * (w1[0] + w1[4] + w1[7]);
    t1[1] = a1 * (w1[1] + w1[5] + w1[8]);
    t1[2] = a1 * (w1[2] + w1[6] + w1[9]);
    t1[3] = a1 * w1[3];
    #pragma unroll
    for (int k = 4; k < NF; ++k) { t0[k] = a0 * w0[k]; t1[k] = a1 * w1[k]; }

    uint4 bd0, bd1;
    unsigned p001 = f2bfu(t0[0]) | (f2bfu(t0[1]) << 16);
    unsigned p023 = f2bfu(t0[2]) | (f2bfu(t0[3]) << 16);
    unsigned p045 = f2bfu(t0[4]) | (f2bfu(t0[5]) << 16);
    unsigned p067 = f2bfu(t0[6]) | (f2bfu(t0[7]) << 16);
    unsigned p089 = f2bfu(t0[8]) | (f2bfu(t0[9]) << 16);
    unsigned p101 = f2bfu(t1[0]) | (f2bfu(t1[1]) << 16);
    unsigned p123 = f2bfu(t1[2]) | (f2bfu(t1[3]) << 16);
    unsigned p145 = f2bfu(t1[4]) | (f2bfu(t1[5]) << 16);
    unsigned p167 = f2bfu(t1[6]) | (f2bfu(t1[7]) << 16);
    unsigned p189 = f2bfu(t1[8]) | (f2bfu(t1[9]) << 16);
    bd0.x = half ? p089 : p001;  bd0.y = half ? 0u : p023;
    bd0.z = half ? 0u : p045;    bd0.w = half ? 0u : p067;
    bd1.x = half ? p189 : p101;  bd1.y = half ? 0u : p123;
    bd1.z = half ? 0u : p145;    bd1.w = half ? 0u : p167;
    bf0 = __builtin_bit_cast(short8, bd0);
    bf1 = __builtin_bit_cast(short8, bd1);
  }

  // prefetch iteration 0
  int vu = __builtin_amdgcn_readfirstlane(waveG);
  int4   rec_n = meanws[vu];
  float4 pt_n  = ((const float4*)vf)[vu * P_ + p];

  #pragma unroll
  for (int it = 0; it < K3_ITERS; ++it) {
    const int4   rec = rec_n;
    const float4 pt  = pt_n;
    const int vcur = vu;
    if (it + 1 < K3_ITERS) {
      vu = __builtin_amdgcn_readfirstlane(waveG + (it + 1) * K3_WAVES);
      rec_n = meanws[vu];
      pt_n  = ((const float4*)vf)[vu * P_ + p];
    }

    const int cnt = rec.w;
    const bool pm = p < cnt;
    unsigned dx = f2bfu(pm ? pt.x : 0.f) | (f2bfu(pm ? pt.y : 0.f) << 16);
    unsigned dy = f2bfu(pm ? pt.z : 0.f) | (f2bfu(pm ? pt.w : 0.f) << 16);
    unsigned m01 = pm ? (unsigned)rec.x : 0u;
    unsigned m23 = pm ? (unsigned)rec.y : 0u;
    unsigned m45 = pm ? (unsigned)rec.z : 0u;
    uint4 adw;
    adw.x = half ? m45 : dx;
    adw.y = half ? 0u  : dy;
    adw.z = half ? 0u  : m01;
    adw.w = half ? 0u  : m23;
    short8 af = __builtin_bit_cast(short8, adw);

    floatx16 c0 = {}, c1 = {};
    c0 = __builtin_amdgcn_mfma_f32_32x32x16_bf16(af, bf0, c0, 0, 0, 0);
    c1 = __builtin_amdgcn_mfma_f32_32x32x16_bf16(af, bf1, c1, 0, 0, 0);

    float m0 = c0[0], m1 = c1[0];
    #pragma unroll
    for (int i = 1; i < 16; ++i) {
      m0 = fmaxf(m0, c0[i]);
      m1 = fmaxf(m1, c1[i]);
    }
    m0 = fmaxf(m0, __shfl_xor(m0, 32, 64));
    m1 = fmaxf(m1, __shfl_xor(m1, 32, 64));
    float y = half ? fmaxf(b1 + m1, 0.f) : fmaxf(b0 + m0, 0.f);
    out[vcur * COUT + lane] = y;
  }
}

extern "C" void kernel_launch(void* const* d_in, const int* in_sizes, int n_in,
                              void* d_out, int out_size, void* d_ws, size_t ws_size,
                              hipStream_t stream)
{
  const float* vf     = (const float*)d_in[0];
  const int*   npts   = (const int*)d_in[1];
  const int*   coords = (const int*)d_in[2];
  const float* Wm     = (const float*)d_in[3];
  const float* gamma  = (const float*)d_in[4];
  const float* beta   = (const float*)d_in[5];
  float* out = (float*)d_out;

  float* ws = (float*)d_ws;
  float* partials = ws;                                // 3125*72 = 225000 floats
  float* ab       = ws + K1_BLOCKS * PSTRIDE;          // 128 floats
  int4*  meanws   = (int4*)(ws + K1_BLOCKS * PSTRIDE + 128);  // 16B-aligned

  k1_stats<<<K1_BLOCKS, 256, 0, stream>>>(vf, npts, coords, partials, meanws);
  k2_finalize<<<1, 1024, 0, stream>>>(partials, Wm, gamma, beta, ab);
  k3_mfma<<<K3_BLOCKS, 256, 0, stream>>>(vf, Wm, ab, meanws, out);
}

// Round 10
// 150.254 us; speedup vs baseline: 2.3703x; 1.4102x over previous
//
#include <hip/hip_runtime.h>

// PillarVFE fused, 3 kernels + tiny memset. Lessons baked in:
//  - R7/R8: device-scope __threadfence per block costs ~0.17us each -> never
//    do cross-block handoff inside a kernel. Atomic adds (no fence) are OK.
//  - R9: single-block k2 reading 3125 rows = 68us (one CU ~25GB/s cap) ->
//    reduce via 16 atomic accumulator rows written by k1, k2 reads only 16.
// k1: 8 thr/voxel (4 pts each), coalesced, register moments P2/T/S, octet
//     shuffle combine, per-lane algebraic epilogue -> 65 f-moments,
//     butterfly {8,16,32}, LDS block reduce, 65 unsafeAtomicAdd into
//     acc[blockIdx&15][.]. Also writes per-voxel packed record.
// k2: one block: sum 16 acc rows (double) -> per-channel a,b.  (~3us)
// k3: A=[xyzw,-mean,-ctr]*mask in MFMA K-slots, B=a*W'' bf16, C=0 -> D=a*x;
//     out = relu(b + max_rows D). One wave = one voxel/iter, prefetched.

typedef __attribute__((ext_vector_type(8))) short short8;     // 8 bf16
typedef __attribute__((ext_vector_type(16))) float floatx16;  // 32x32 MFMA C/D

namespace {
constexpr int V_    = 100000;
constexpr int P_    = 32;
constexpr int COUT  = 64;
constexpr int NF    = 10;
constexpr int NMOM  = 65;
constexpr int PSTRIDE = 72;
constexpr int NSETS  = 16;        // atomic accumulator rows
constexpr int K1_BLOCKS = 3125;   // 32 voxels/block (8 thr/voxel) -> exact
constexpr int K3_BLOCKS = 3125;   // 12500 waves x 8 iters = 100000 exactly
constexpr int K3_WAVES  = 12500;
constexpr int K3_ITERS  = 8;

constexpr float VX_ = 0.16f, VY_ = 0.16f, VZ_ = 4.0f;
constexpr float XOFF_ = 0.08f, YOFF_ = -39.60f, ZOFF_ = -1.0f;
constexpr float EPS_ = 0.001f;
}

__device__ __forceinline__ unsigned f2bfu(float x) {  // RNE -> 16-bit value
  unsigned u = __builtin_bit_cast(unsigned, x);
  u += 0x7fffu + ((u >> 16) & 1u);
  return u >> 16;
}

// ---------------- Pass 1 ----------------
__global__ __launch_bounds__(256) void k1_stats(
    const float* __restrict__ vf, const int* __restrict__ npts,
    const int* __restrict__ coords, float* __restrict__ acc,
    int4* __restrict__ meanws)
{
  __shared__ float red[4][NMOM];

  const int tid = threadIdx.x;
  const int gt  = blockIdx.x * 256 + tid;
  const int v   = gt >> 3;          // voxel (exact: 3125*32 = 100000)
  const int oct = gt & 7;           // 4-point slice within voxel

  const int  cnt = npts[v];
  const int4 cd  = ((const int4*)coords)[v];

  // 4 float4 loads: 64B/thread -> wave covers 4KB contiguous
  float4 q[4];
  const float4* base = (const float4*)vf + (size_t)v * P_ + oct * 4;
  #pragma unroll
  for (int i = 0; i < 4; ++i) q[i] = base[i];

  float p2[10];
  #pragma unroll
  for (int i = 0; i < 10; ++i) p2[i] = 0.f;
  float tx = 0.f, ty = 0.f, tz = 0.f, tw = 0.f;
  float sx = 0.f, sy = 0.f, sz = 0.f;

  #pragma unroll
  for (int i = 0; i < 4; ++i) {
    const int p = oct * 4 + i;
    const float msk = (p < cnt) ? 1.f : 0.f;
    sx += q[i].x; sy += q[i].y; sz += q[i].z;
    const float ux = q[i].x * msk, uy = q[i].y * msk;
    const float uz = q[i].z * msk, uw = q[i].w * msk;
    tx += ux; ty += uy; tz += uz; tw += uw;
    p2[0] += ux*ux; p2[1] += ux*uy; p2[2] += ux*uz; p2[3] += ux*uw;
    p2[4] += uy*uy; p2[5] += uy*uz; p2[6] += uy*uw;
    p2[7] += uz*uz; p2[8] += uz*uw;
    p2[9] += uw*uw;
  }

  // combine the voxel's 8 threads (xor 1,2,4): 17 additive raw moments
  #pragma unroll
  for (int m = 1; m <= 4; m <<= 1) {
    sx += __shfl_xor(sx, m, 64); sy += __shfl_xor(sy, m, 64);
    sz += __shfl_xor(sz, m, 64);
    tx += __shfl_xor(tx, m, 64); ty += __shfl_xor(ty, m, 64);
    tz += __shfl_xor(tz, m, 64); tw += __shfl_xor(tw, m, 64);
    #pragma unroll
    for (int i = 0; i < 10; ++i) p2[i] += __shfl_xor(p2[i], m, 64);
  }

  const float cf = (cnt > 0) ? (float)cnt : 1.f;
  const float rinv = 1.f / cf;
  const float gx = sx * rinv, gy = sy * rinv, gz = sz * rinv;
  const float hx = (float)cd.w * VX_ + XOFF_;
  const float hy = (float)cd.z * VY_ + YOFF_;
  const float hz = (float)cd.y * VZ_ + ZOFF_;

  if (oct == 0) {   // packed record for k3
    unsigned nm01 = f2bfu(-gx) | (f2bfu(-gy) << 16);
    unsigned nm23 = f2bfu(-gz) | (f2bfu(-hx) << 16);
    unsigned nm45 = f2bfu(-hy) | (f2bfu(-hz) << 16);
    meanws[v] = make_int4((int)nm01, (int)nm23, (int)nm45, cnt);
  }

  // f-moment reconstruction (replicated across octet):
  // M1_i = T[SIG[i]] - cnt*K[i]
  // M2_ij = P2[SIG i,SIG j] - K_i*T[SIG j] - K_j*T[SIG i] + cnt*K_i*K_j
  float mom[NMOM];
  {
    const int SIG[10] = {0,1,2,3, 0,1,2, 0,1,2};
    const float K[10] = {0.f,0.f,0.f,0.f, gx,gy,gz, hx,hy,hz};
    const float Tm[4] = {tx,ty,tz,tw};
    const int I44[4][4] = {{0,1,2,3},{1,4,5,6},{2,5,7,8},{3,6,8,9}};

    #pragma unroll
    for (int i = 0; i < 10; ++i) mom[i] = Tm[SIG[i]] - cf * K[i];
    int idx = NF;
    #pragma unroll
    for (int i = 0; i < 10; ++i)
      #pragma unroll
      for (int j = i; j < 10; ++j) {
        mom[idx++] = p2[I44[SIG[i]][SIG[j]]]
                   - K[i] * Tm[SIG[j]] - K[j] * Tm[SIG[i]]
                   + cf * K[i] * K[j];
      }
  }

  // octet-level butterfly: sums the wave's 8 octets (each voxel once)
  #pragma unroll
  for (int i = 0; i < NMOM; ++i) {
    float a = mom[i];
    #pragma unroll
    for (int m = 8; m <= 32; m <<= 1) a += __shfl_xor(a, m, 64);
    mom[i] = a;
  }
  if ((tid & 63) == 0) {
    int w = tid >> 6;
    #pragma unroll
    for (int i = 0; i < NMOM; ++i) red[w][i] = mom[i];
  }
  __syncthreads();
  if (tid < NMOM) {
    const float val =
        (red[0][tid] + red[1][tid]) + (red[2][tid] + red[3][tid]);
    // HW fp32 atomic (no fence). Depth ~195 per address across 16 sets.
    unsafeAtomicAdd(&acc[(blockIdx.x & (NSETS - 1)) * PSTRIDE + tid], val);
  }
}

// ---------------- Pass 2: 16 rows -> a,b ----------------
__global__ __launch_bounds__(256) void k2_finalize(
    const float* __restrict__ acc, const float* __restrict__ Wm,
    const float* __restrict__ gamma, const float* __restrict__ beta,
    float* __restrict__ ab)
{
  __shared__ double Sd[NMOM];
  const int t = threadIdx.x;

  if (t < NMOM) {
    double d = 0.0;
    #pragma unroll
    for (int r = 0; r < NSETS; ++r) d += (double)acc[r * PSTRIDE + t];
    Sd[t] = d;
  }
  __syncthreads();
  if (t < COUT) {
    const double N = (double)V_ * (double)P_;
    double w[NF];
    #pragma unroll
    for (int c = 0; c < NF; ++c) w[c] = (double)Wm[t * NF + c];
    double mean = 0.0;
    #pragma unroll
    for (int c = 0; c < NF; ++c) mean += w[c] * Sd[c];
    mean /= N;
    double ex2 = 0.0;
    int idx = NF;
    #pragma unroll
    for (int c = 0; c < NF; ++c)
      #pragma unroll
      for (int c2 = c; c2 < NF; ++c2) {
        double coef = (c == c2) ? 1.0 : 2.0;
        ex2 += coef * w[c] * w[c2] * Sd[idx++];
      }
    ex2 /= N;
    double var = ex2 - mean * mean;
    double rs = 1.0 / sqrt(var + (double)EPS_);
    double a = (double)gamma[t] * rs;
    double b = (double)beta[t] - mean * a;
    ab[t] = (float)a;
    ab[COUT + t] = (float)b;
  }
}

// ---------------- Pass 3 ----------------
__global__ __launch_bounds__(256) void k3_mfma(
    const float* __restrict__ vf, const float* __restrict__ Wm,
    const float* __restrict__ ab, const int4* __restrict__ meanws,
    float* __restrict__ out)
{
  const int tid  = threadIdx.x;
  const int lane = tid & 63;
  const int p    = lane & 31;
  const int half = lane >> 5;
  const int waveG = blockIdx.x * 4 + (tid >> 6);   // 0..12499

  // B fragments: B[k][n], n = lane&31, k = half*8+j.
  // k0..3: a*(W0+W4+W7, W1+W5+W8, W2+W6+W9, W3); k4..9: a*(W4..W9).
  const float a0 = ab[p],      b0 = ab[COUT + p];
  const float a1 = ab[32 + p], b1 = ab[COUT + 32 + p];
  short8 bf0, bf1;
  {
    const float* w0 = &Wm[p * NF];
    const float* w1 = &Wm[(32 + p) * NF];
    float t0[NF], t1[NF];
    t0[0] = a0 * (w0[0] + w0[4] + w0[7]);
    t0[1] = a0 * (w0[1] + w0[5] + w0[8]);
    t0[2] = a0 * (w0[2] + w0[6] + w0[9]);
    t0[3] = a0 * w0[3];
    t1[0] = a1 * (w1[0] + w1[4] + w1[7]);
    t1[1] = a1 * (w1[1] + w1[5] + w1[8]);
    t1[2] = a1 * (w1[2] + w1[6] + w1[9]);
    t1[3] = a1 * w1[3];
    #pragma unroll
    for (int k = 4; k < NF; ++k) { t0[k] = a0 * w0[k]; t1[k] = a1 * w1[k]; }

    uint4 bd0, bd1;
    unsigned p001 = f2bfu(t0[0]) | (f2bfu(t0[1]) << 16);
    unsigned p023 = f2bfu(t0[2]) | (f2bfu(t0[3]) << 16);
    unsigned p045 = f2bfu(t0[4]) | (f2bfu(t0[5]) << 16);
    unsigned p067 = f2bfu(t0[6]) | (f2bfu(t0[7]) << 16);
    unsigned p089 = f2bfu(t0[8]) | (f2bfu(t0[9]) << 16);
    unsigned p101 = f2bfu(t1[0]) | (f2bfu(t1[1]) << 16);
    unsigned p123 = f2bfu(t1[2]) | (f2bfu(t1[3]) << 16);
    unsigned p145 = f2bfu(t1[4]) | (f2bfu(t1[5]) << 16);
    unsigned p167 = f2bfu(t1[6]) | (f2bfu(t1[7]) << 16);
    unsigned p189 = f2bfu(t1[8]) | (f2bfu(t1[9]) << 16);
    bd0.x = half ? p089 : p001;  bd0.y = half ? 0u : p023;
    bd0.z = half ? 0u : p045;    bd0.w = half ? 0u : p067;
    bd1.x = half ? p189 : p101;  bd1.y = half ? 0u : p123;
    bd1.z = half ? 0u : p145;    bd1.w = half ? 0u : p167;
    bf0 = __builtin_bit_cast(short8, bd0);
    bf1 = __builtin_bit_cast(short8, bd1);
  }

  // prefetch iteration 0
  int vu = __builtin_amdgcn_readfirstlane(waveG);
  int4   rec_n = meanws[vu];
  float4 pt_n  = ((const float4*)vf)[vu * P_ + p];

  #pragma unroll
  for (int it = 0; it < K3_ITERS; ++it) {
    const int4   rec = rec_n;
    const float4 pt  = pt_n;
    const int vcur = vu;
    if (it + 1 < K3_ITERS) {
      vu = __builtin_amdgcn_readfirstlane(waveG + (it + 1) * K3_WAVES);
      rec_n = meanws[vu];
      pt_n  = ((const float4*)vf)[vu * P_ + p];
    }

    const int cnt = rec.w;
    const bool pm = p < cnt;
    unsigned dx = f2bfu(pm ? pt.x : 0.f) | (f2bfu(pm ? pt.y : 0.f) << 16);
    unsigned dy = f2bfu(pm ? pt.z : 0.f) | (f2bfu(pm ? pt.w : 0.f) << 16);
    unsigned m01 = pm ? (unsigned)rec.x : 0u;
    unsigned m23 = pm ? (unsigned)rec.y : 0u;
    unsigned m45 = pm ? (unsigned)rec.z : 0u;
    uint4 adw;
    adw.x = half ? m45 : dx;
    adw.y = half ? 0u  : dy;
    adw.z = half ? 0u  : m01;
    adw.w = half ? 0u  : m23;
    short8 af = __builtin_bit_cast(short8, adw);

    floatx16 c0 = {}, c1 = {};
    c0 = __builtin_amdgcn_mfma_f32_32x32x16_bf16(af, bf0, c0, 0, 0, 0);
    c1 = __builtin_amdgcn_mfma_f32_32x32x16_bf16(af, bf1, c1, 0, 0, 0);

    float m0 = c0[0], m1 = c1[0];
    #pragma unroll
    for (int i = 1; i < 16; ++i) {
      m0 = fmaxf(m0, c0[i]);
      m1 = fmaxf(m1, c1[i]);
    }
    m0 = fmaxf(m0, __shfl_xor(m0, 32, 64));
    m1 = fmaxf(m1, __shfl_xor(m1, 32, 64));
    float y = half ? fmaxf(b1 + m1, 0.f) : fmaxf(b0 + m0, 0.f);
    out[vcur * COUT + lane] = y;
  }
}

extern "C" void kernel_launch(void* const* d_in, const int* in_sizes, int n_in,
                              void* d_out, int out_size, void* d_ws, size_t ws_size,
                              hipStream_t stream)
{
  const float* vf     = (const float*)d_in[0];
  const int*   npts   = (const int*)d_in[1];
  const int*   coords = (const int*)d_in[2];
  const float* Wm     = (const float*)d_in[3];
  const float* gamma  = (const float*)d_in[4];
  const float* beta   = (const float*)d_in[5];
  float* out = (float*)d_out;

  float* ws = (float*)d_ws;
  float* acc    = ws;                            // 16*72 floats (atomic sets)
  float* ab     = ws + NSETS * PSTRIDE;          // 128 floats
  int4*  meanws = (int4*)(ws + NSETS * PSTRIDE + 128);  // V_ int4, 16B-aligned

  hipMemsetAsync(acc, 0, NSETS * PSTRIDE * sizeof(float), stream);
  k1_stats<<<K1_BLOCKS, 256, 0, stream>>>(vf, npts, coords, acc, meanws);
  k2_finalize<<<1, 256, 0, stream>>>(acc, Wm, gamma, beta, ab);
  k3_mfma<<<K3_BLOCKS, 256, 0, stream>>>(vf, Wm, ab, meanws, out);
}

// Round 11
// 133.190 us; speedup vs baseline: 2.6740x; 1.1281x over previous
//
#include <hip/hip_runtime.h>

// PillarVFE fused, 3 kernels + tiny memset. Measured lessons baked in:
//  - R7/R8: device-scope __threadfence per block ~0.17us each -> no
//    cross-block handoff inside a kernel. Plain fp32 HW atomics are OK (R10).
//  - R9: single-block k2 reading 3125 rows = 68us -> k1 reduces via 16
//    atomic accumulator rows; k2 reads only 16 (R10: ~3us).
//  - R10: 3125 short k1 blocks = per-block tail latency dominated (45us,
//    VALU 19%) -> R11: 625 blocks x 5 tiles, tail amortized 5x, whole grid
//    co-resident.
// k1: 8 thr/voxel (4 pts each), coalesced; 5 tiles/block accumulated in
//     registers (65 f-moments); octet shuffle-combine per tile; single
//     butterfly {8,16,32} + LDS reduce + 65 unsafeAtomicAdd at block end.
//     Writes per-voxel packed record (-mean,-center bf16, cnt).
// k2: one block: sum 16 acc rows (double) -> per-channel a,b.
// k3: A=[xyzw,-mean,-ctr]*mask in MFMA K-slots, B=a*W'' bf16, C=0 -> D=a*x;
//     out = relu(b + max_rows D). One wave = one voxel/iter, prefetched.

typedef __attribute__((ext_vector_type(8))) short short8;     // 8 bf16
typedef __attribute__((ext_vector_type(16))) float floatx16;  // 32x32 MFMA C/D

namespace {
constexpr int V_    = 100000;
constexpr int P_    = 32;
constexpr int COUT  = 64;
constexpr int NF    = 10;
constexpr int NMOM  = 65;
constexpr int PSTRIDE = 72;
constexpr int NSETS  = 16;        // atomic accumulator rows
constexpr int K1_BLOCKS = 625;    // x 5 tiles x 32 voxels = 100000 exact
constexpr int K1_TILES  = 5;
constexpr int K3_BLOCKS = 3125;   // 12500 waves x 8 iters = 100000 exactly
constexpr int K3_WAVES  = 12500;
constexpr int K3_ITERS  = 8;

constexpr float VX_ = 0.16f, VY_ = 0.16f, VZ_ = 4.0f;
constexpr float XOFF_ = 0.08f, YOFF_ = -39.60f, ZOFF_ = -1.0f;
constexpr float EPS_ = 0.001f;
}

__device__ __forceinline__ unsigned f2bfu(float x) {  // RNE -> 16-bit value
  unsigned u = __builtin_bit_cast(unsigned, x);
  u += 0x7fffu + ((u >> 16) & 1u);
  return u >> 16;
}

// ---------------- Pass 1 ----------------
__global__ __launch_bounds__(256) void k1_stats(
    const float* __restrict__ vf, const int* __restrict__ npts,
    const int* __restrict__ coords, float* __restrict__ acc,
    int4* __restrict__ meanws)
{
  __shared__ float red[4][NMOM];

  const int tid = threadIdx.x;
  const int oct = tid & 7;          // 4-point slice within voxel
  const int vlane = tid >> 3;       // voxel-in-tile (0..31)

  float macc[NMOM];
  #pragma unroll
  for (int i = 0; i < NMOM; ++i) macc[i] = 0.f;

  #pragma unroll
  for (int it = 0; it < K1_TILES; ++it) {
    const int tile = blockIdx.x * K1_TILES + it;   // 0..3124
    const int v = tile * 32 + vlane;

    const int  cnt = npts[v];
    const int4 cd  = ((const int4*)coords)[v];

    // 4 float4 loads: 64B/thread -> wave covers 4KB contiguous
    float4 q[4];
    const float4* base = (const float4*)vf + (size_t)v * P_ + oct * 4;
    #pragma unroll
    for (int i = 0; i < 4; ++i) q[i] = base[i];

    float p2[10];
    #pragma unroll
    for (int i = 0; i < 10; ++i) p2[i] = 0.f;
    float tx = 0.f, ty = 0.f, tz = 0.f, tw = 0.f;
    float sx = 0.f, sy = 0.f, sz = 0.f;

    #pragma unroll
    for (int i = 0; i < 4; ++i) {
      const int p = oct * 4 + i;
      const float msk = (p < cnt) ? 1.f : 0.f;
      sx += q[i].x; sy += q[i].y; sz += q[i].z;
      const float ux = q[i].x * msk, uy = q[i].y * msk;
      const float uz = q[i].z * msk, uw = q[i].w * msk;
      tx += ux; ty += uy; tz += uz; tw += uw;
      p2[0] += ux*ux; p2[1] += ux*uy; p2[2] += ux*uz; p2[3] += ux*uw;
      p2[4] += uy*uy; p2[5] += uy*uz; p2[6] += uy*uw;
      p2[7] += uz*uz; p2[8] += uz*uw;
      p2[9] += uw*uw;
    }

    // combine the voxel's 8 threads (xor 1,2,4): 17 additive raw moments
    #pragma unroll
    for (int m = 1; m <= 4; m <<= 1) {
      sx += __shfl_xor(sx, m, 64); sy += __shfl_xor(sy, m, 64);
      sz += __shfl_xor(sz, m, 64);
      tx += __shfl_xor(tx, m, 64); ty += __shfl_xor(ty, m, 64);
      tz += __shfl_xor(tz, m, 64); tw += __shfl_xor(tw, m, 64);
      #pragma unroll
      for (int i = 0; i < 10; ++i) p2[i] += __shfl_xor(p2[i], m, 64);
    }

    const float cf = (cnt > 0) ? (float)cnt : 1.f;
    const float rinv = 1.f / cf;
    const float gx = sx * rinv, gy = sy * rinv, gz = sz * rinv;
    const float hx = (float)cd.w * VX_ + XOFF_;
    const float hy = (float)cd.z * VY_ + YOFF_;
    const float hz = (float)cd.y * VZ_ + ZOFF_;

    if (oct == 0) {   // packed record for k3
      unsigned nm01 = f2bfu(-gx) | (f2bfu(-gy) << 16);
      unsigned nm23 = f2bfu(-gz) | (f2bfu(-hx) << 16);
      unsigned nm45 = f2bfu(-hy) | (f2bfu(-hz) << 16);
      meanws[v] = make_int4((int)nm01, (int)nm23, (int)nm45, cnt);
    }

    // f-moment reconstruction (replicated across octet), accumulated:
    // M1_i = T[SIG[i]] - cnt*K[i]
    // M2_ij = P2[SIG i,SIG j] - K_i*T[SIG j] - K_j*T[SIG i] + cnt*K_i*K_j
    {
      const int SIG[10] = {0,1,2,3, 0,1,2, 0,1,2};
      const float K[10] = {0.f,0.f,0.f,0.f, gx,gy,gz, hx,hy,hz};
      const float Tm[4] = {tx,ty,tz,tw};
      const int I44[4][4] = {{0,1,2,3},{1,4,5,6},{2,5,7,8},{3,6,8,9}};

      #pragma unroll
      for (int i = 0; i < 10; ++i) macc[i] += Tm[SIG[i]] - cf * K[i];
      int idx = NF;
      #pragma unroll
      for (int i = 0; i < 10; ++i)
        #pragma unroll
        for (int j = i; j < 10; ++j) {
          macc[idx++] += p2[I44[SIG[i]][SIG[j]]]
                       - K[i] * Tm[SIG[j]] - K[j] * Tm[SIG[i]]
                       + cf * K[i] * K[j];
        }
    }
  }

  // octet-level butterfly: sums the wave's 8 octets (each voxel once)
  #pragma unroll
  for (int i = 0; i < NMOM; ++i) {
    float a = macc[i];
    #pragma unroll
    for (int m = 8; m <= 32; m <<= 1) a += __shfl_xor(a, m, 64);
    macc[i] = a;
  }
  if ((tid & 63) == 0) {
    int w = tid >> 6;
    #pragma unroll
    for (int i = 0; i < NMOM; ++i) red[w][i] = macc[i];
  }
  __syncthreads();
  if (tid < NMOM) {
    const float val =
        (red[0][tid] + red[1][tid]) + (red[2][tid] + red[3][tid]);
    // HW fp32 atomic (no fence). Depth ~39 per address across 16 sets.
    unsafeAtomicAdd(&acc[(blockIdx.x & (NSETS - 1)) * PSTRIDE + tid], val);
  }
}

// ---------------- Pass 2: 16 rows -> a,b ----------------
__global__ __launch_bounds__(256) void k2_finalize(
    const float* __restrict__ acc, const float* __restrict__ Wm,
    const float* __restrict__ gamma, const float* __restrict__ beta,
    float* __restrict__ ab)
{
  __shared__ double Sd[NMOM];
  const int t = threadIdx.x;

  if (t < NMOM) {
    double d = 0.0;
    #pragma unroll
    for (int r = 0; r < NSETS; ++r) d += (double)acc[r * PSTRIDE + t];
    Sd[t] = d;
  }
  __syncthreads();
  if (t < COUT) {
    const double N = (double)V_ * (double)P_;
    double w[NF];
    #pragma unroll
    for (int c = 0; c < NF; ++c) w[c] = (double)Wm[t * NF + c];
    double mean = 0.0;
    #pragma unroll
    for (int c = 0; c < NF; ++c) mean += w[c] * Sd[c];
    mean /= N;
    double ex2 = 0.0;
    int idx = NF;
    #pragma unroll
    for (int c = 0; c < NF; ++c)
      #pragma unroll
      for (int c2 = c; c2 < NF; ++c2) {
        double coef = (c == c2) ? 1.0 : 2.0;
        ex2 += coef * w[c] * w[c2] * Sd[idx++];
      }
    ex2 /= N;
    double var = ex2 - mean * mean;
    double rs = 1.0 / sqrt(var + (double)EPS_);
    double a = (double)gamma[t] * rs;
    double b = (double)beta[t] - mean * a;
    ab[t] = (float)a;
    ab[COUT + t] = (float)b;
  }
}

// ---------------- Pass 3 ----------------
__global__ __launch_bounds__(256) void k3_mfma(
    const float* __restrict__ vf, const float* __restrict__ Wm,
    const float* __restrict__ ab, const int4* __restrict__ meanws,
    float* __restrict__ out)
{
  const int tid  = threadIdx.x;
  const int lane = tid & 63;
  const int p    = lane & 31;
  const int half = lane >> 5;
  const int waveG = blockIdx.x * 4 + (tid >> 6);   // 0..12499

  // B fragments: B[k][n], n = lane&31, k = half*8+j.
  // k0..3: a*(W0+W4+W7, W1+W5+W8, W2+W6+W9, W3); k4..9: a*(W4..W9).
  const float a0 = ab[p],      b0 = ab[COUT + p];
  const float a1 = ab[32 + p], b1 = ab[COUT + 32 + p];
  short8 bf0, bf1;
  {
    const float* w0 = &Wm[p * NF];
    const float* w1 = &Wm[(32 + p) * NF];
    float t0[NF], t1[NF];
    t0[0] = a0 * (w0[0] + w0[4] + w0[7]);
    t0[1] = a0 * (w0[1] + w0[5] + w0[8]);
    t0[2] = a0 * (w0[2] + w0[6] + w0[9]);
    t0[3] = a0 * w0[3];
    t1[0] = a1 * (w1[0] + w1[4] + w1[7]);
    t1[1] = a1 * (w1[1] + w1[5] + w1[8]);
    t1[2] = a1 * (w1[2] + w1[6] + w1[9]);
    t1[3] = a1 * w1[3];
    #pragma unroll
    for (int k = 4; k < NF; ++k) { t0[k] = a0 * w0[k]; t1[k] = a1 * w1[k]; }

    uint4 bd0, bd1;
    unsigned p001 = f2bfu(t0[0]) | (f2bfu(t0[1]) << 16);
    unsigned p023 = f2bfu(t0[2]) | (f2bfu(t0[3]) << 16);
    unsigned p045 = f2bfu(t0[4]) | (f2bfu(t0[5]) << 16);
    unsigned p067 = f2bfu(t0[6]) | (f2bfu(t0[7]) << 16);
    unsigned p089 = f2bfu(t0[8]) | (f2bfu(t0[9]) << 16);
    unsigned p101 = f2bfu(t1[0]) | (f2bfu(t1[1]) << 16);
    unsigned p123 = f2bfu(t1[2]) | (f2bfu(t1[3]) << 16);
    unsigned p145 = f2bfu(t1[4]) | (f2bfu(t1[5]) << 16);
    unsigned p167 = f2bfu(t1[6]) | (f2bfu(t1[7]) << 16);
    unsigned p189 = f2bfu(t1[8]) | (f2bfu(t1[9]) << 16);
    bd0.x = half ? p089 : p001;  bd0.y = half ? 0u : p023;
    bd0.z = half ? 0u : p045;    bd0.w = half ? 0u : p067;
    bd1.x = half ? p189 : p101;  bd1.y = half ? 0u : p123;
    bd1.z = half ? 0u : p145;    bd1.w = half ? 0u : p167;
    bf0 = __builtin_bit_cast(short8, bd0);
    bf1 = __builtin_bit_cast(short8, bd1);
  }

  // prefetch iteration 0
  int vu = __builtin_amdgcn_readfirstlane(waveG);
  int4   rec_n = meanws[vu];
  float4 pt_n  = ((const float4*)vf)[vu * P_ + p];

  #pragma unroll
  for (int it = 0; it < K3_ITERS; ++it) {
    const int4   rec = rec_n;
    const float4 pt  = pt_n;
    const int vcur = vu;
    if (it + 1 < K3_ITERS) {
      vu = __builtin_amdgcn_readfirstlane(waveG + (it + 1) * K3_WAVES);
      rec_n = meanws[vu];
      pt_n  = ((const float4*)vf)[vu * P_ + p];
    }

    const int cnt = rec.w;
    const bool pm = p < cnt;
    unsigned dx = f2bfu(pm ? pt.x : 0.f) | (f2bfu(pm ? pt.y : 0.f) << 16);
    unsigned dy = f2bfu(pm ? pt.z : 0.f) | (f2bfu(pm ? pt.w : 0.f) << 16);
    unsigned m01 = pm ? (unsigned)rec.x : 0u;
    unsigned m23 = pm ? (unsigned)rec.y : 0u;
    unsigned m45 = pm ? (unsigned)rec.z : 0u;
    uint4 adw;
    adw.x = half ? m45 : dx;
    adw.y = half ? 0u  : dy;
    adw.z = half ? 0u  : m01;
    adw.w = half ? 0u  : m23;
    short8 af = __builtin_bit_cast(short8, adw);

    floatx16 c0 = {}, c1 = {};
    c0 = __builtin_amdgcn_mfma_f32_32x32x16_bf16(af, bf0, c0, 0, 0, 0);
    c1 = __builtin_amdgcn_mfma_f32_32x32x16_bf16(af, bf1, c1, 0, 0, 0);

    float m0 = c0[0], m1 = c1[0];
    #pragma unroll
    for (int i = 1; i < 16; ++i) {
      m0 = fmaxf(m0, c0[i]);
      m1 = fmaxf(m1, c1[i]);
    }
    m0 = fmaxf(m0, __shfl_xor(m0, 32, 64));
    m1 = fmaxf(m1, __shfl_xor(m1, 32, 64));
    float y = half ? fmaxf(b1 + m1, 0.f) : fmaxf(b0 + m0, 0.f);
    out[vcur * COUT + lane] = y;
  }
}

extern "C" void kernel_launch(void* const* d_in, const int* in_sizes, int n_in,
                              void* d_out, int out_size, void* d_ws, size_t ws_size,
                              hipStream_t stream)
{
  const float* vf     = (const float*)d_in[0];
  const int*   npts   = (const int*)d_in[1];
  const int*   coords = (const int*)d_in[2];
  const float* Wm     = (const float*)d_in[3];
  const float* gamma  = (const float*)d_in[4];
  const float* beta   = (const float*)d_in[5];
  float* out = (float*)d_out;

  float* ws = (float*)d_ws;
  float* acc    = ws;                            // 16*72 floats (atomic sets)
  float* ab     = ws + NSETS * PSTRIDE;          // 128 floats
  int4*  meanws = (int4*)(ws + NSETS * PSTRIDE + 128);  // V_ int4, 16B-aligned

  hipMemsetAsync(acc, 0, NSETS * PSTRIDE * sizeof(float), stream);
  k1_stats<<<K1_BLOCKS, 256, 0, stream>>>(vf, npts, coords, acc, meanws);
  k2_finalize<<<1, 256, 0, stream>>>(acc, Wm, gamma, beta, ab);
  k3_mfma<<<K3_BLOCKS, 256, 0, stream>>>(vf, Wm, ab, meanws, out);
}